// Round 1
// baseline (235.010 us; speedup 1.0000x reference)
//
#include <hip/hip_runtime.h>
#include <math.h>

// Problem: B = C = HW = 64. Two input pairs (f1_0,f2_0), (f1_1,f2_1).
// loss = mean over (b,c) of Sinkhorn transport cost with cost matrix C[c]
// (cosine-distance matrix of batch c, row min/max normalized), marginals
// softmax(x1[b,c,:]) / softmax(x2[b,c,:]). Averaged over the two pairs.

#define SINK_ITERS 5
#define EPS_F 0.5f
#define INV_EPS 2.0f
#define LOGEPS 1e-12f
#define COSEPS 1e-8f

__device__ __forceinline__ float wave_sum(float v) {
    #pragma unroll
    for (int o = 32; o; o >>= 1) v += __shfl_xor(v, o);
    return v;
}
__device__ __forceinline__ float wave_max(float v) {
    #pragma unroll
    for (int o = 32; o; o >>= 1) v = fmaxf(v, __shfl_xor(v, o));
    return v;
}

// ---------------------------------------------------------------------------
// Kernel 1: cost matrices. grid = (c=64, p=2), block = 256.
// C[p][c][i][j] = rownorm( 1 - cos(x1[c,i,:], x2[c,j,:]) )
// ---------------------------------------------------------------------------
__global__ __launch_bounds__(256) void build_cost(
        const float* __restrict__ f10, const float* __restrict__ f11,
        const float* __restrict__ f20, const float* __restrict__ f21,
        float* __restrict__ Cout)
{
    const int c = blockIdx.x;
    const int p = blockIdx.y;
    const float* x1 = p ? f11 : f10;
    const float* x2 = p ? f21 : f20;

    __shared__ float X1[64][65];   // pad -> 2-way bank alias only (free)
    __shared__ float X2[64][65];
    __shared__ float Cm[64][65];
    __shared__ float inv1[64], inv2[64];

    const int tid = threadIdx.x;
    const int base = c << 12;      // c * 64*64

    for (int e = tid; e < 4096; e += 256) {
        int r = e >> 6, k = e & 63;
        X1[r][k] = x1[base + e];
        X2[r][k] = x2[base + e];
    }
    __syncthreads();

    if (tid < 128) {
        int r = tid & 63;
        const float* row = (tid < 64) ? X1[r] : X2[r];
        float s = 0.f;
        #pragma unroll 8
        for (int k = 0; k < 64; k++) { float v = row[k]; s += v * v; }
        float inv = 1.0f / fmaxf(sqrtf(s), COSEPS);
        if (tid < 64) inv1[r] = inv; else inv2[r] = inv;
    }
    __syncthreads();

    for (int e = tid; e < 4096; e += 256) {
        int i = e >> 6, j = e & 63;   // i uniform per wave -> X1 row broadcast
        float acc = 0.f;
        #pragma unroll 8
        for (int k = 0; k < 64; k++) acc += X1[i][k] * X2[j][k];
        Cm[i][j] = 1.0f - acc * inv1[i] * inv2[j];
    }
    __syncthreads();

    const int w = tid >> 6, lane = tid & 63;
    for (int i = w; i < 64; i += 4) {
        float v = Cm[i][lane];
        float mn = v, mx = v;
        #pragma unroll
        for (int o = 32; o; o >>= 1) {
            mn = fminf(mn, __shfl_xor(mn, o));
            mx = fmaxf(mx, __shfl_xor(mx, o));
        }
        Cout[(((p << 6) | c) << 12) + (i << 6) + lane] = (v - mn) / (mx - mn);
    }
}

// ---------------------------------------------------------------------------
// Kernel 2: Sinkhorn. grid = (bg=16, c=64, p=2), block = 256 (4 waves).
// Each wave owns one b; block shares Cd = C[c]/eps in LDS.
// u-cancellation: u_new = eps*(logp1 - LSE_t((v_t - C_st)/eps)) (exact in R).
// Work in scaled domain: ut = u/eps, vt = v/eps.
// ---------------------------------------------------------------------------
__global__ __launch_bounds__(256) void sinkhorn(
        const float* __restrict__ f10, const float* __restrict__ f11,
        const float* __restrict__ f20, const float* __restrict__ f21,
        const float* __restrict__ Cmats, float* __restrict__ out)
{
    __shared__ float Cd[64][65];
    __shared__ float vsh[4][64];
    __shared__ float ush[4][64];
    __shared__ float bsum[4];

    const int tid = threadIdx.x, w = tid >> 6, lane = tid & 63;
    const int bg = blockIdx.x, c = blockIdx.y, p = blockIdx.z;
    const float* x1 = p ? f11 : f10;
    const float* x2 = p ? f21 : f20;
    const int b = (bg << 2) | w;

    const float* Cg = Cmats + (((p << 6) | c) << 12);
    for (int e = tid; e < 4096; e += 256)
        Cd[e >> 6][e & 63] = Cg[e] * INV_EPS;

    // log(softmax + 1e-12) rows, one element per lane
    const int rowoff = ((b << 6) | c) << 6;
    float xv1 = x1[rowoff + lane];
    float m1 = wave_max(xv1);
    float e1 = __expf(xv1 - m1);
    float s1 = wave_sum(e1);
    float lp1 = __logf(e1 / s1 + LOGEPS);

    float xv2 = x2[rowoff + lane];
    float m2 = wave_max(xv2);
    float e2 = __expf(xv2 - m2);
    float s2 = wave_sum(e2);
    float lp2 = __logf(e2 / s2 + LOGEPS);

    float u = 0.f;
    vsh[w][lane] = 0.f;
    __syncthreads();   // Cd loaded + v initialized

    for (int it = 0; it < SINK_ITERS; it++) {
        // u-update: lane = s, LSE over t. vsh[w][t] is an LDS broadcast read.
        float m = -1e30f;
        #pragma unroll 8
        for (int t = 0; t < 64; t++)
            m = fmaxf(m, vsh[w][t] - Cd[lane][t]);
        float s = 0.f;
        #pragma unroll 8
        for (int t = 0; t < 64; t++)
            s += __expf(vsh[w][t] - Cd[lane][t] - m);
        u = lp1 - (m + __logf(s));
        ush[w][lane] = u;
        __syncthreads();

        // v-update: lane = t, LSE over s. Cd[si][lane]: banks (si+t)%32 -> 2-way.
        m = -1e30f;
        #pragma unroll 8
        for (int si = 0; si < 64; si++)
            m = fmaxf(m, ush[w][si] - Cd[si][lane]);
        s = 0.f;
        #pragma unroll 8
        for (int si = 0; si < 64; si++)
            s += __expf(ush[w][si] - Cd[si][lane] - m);
        float v = lp2 - (m + __logf(s));
        vsh[w][lane] = v;
        __syncthreads();
    }

    // loss contribution: sum_{s,t} exp(u_s + v_t - Cd_st) * (Cd_st * eps)
    float acc = 0.f;
    #pragma unroll 8
    for (int t = 0; t < 64; t++) {
        float cd = Cd[lane][t];
        acc += __expf(u + vsh[w][t] - cd) * (cd * EPS_F);
    }
    acc = wave_sum(acc);
    if (lane == 0) bsum[w] = acc;
    __syncthreads();
    if (tid == 0)
        atomicAdd(out, (bsum[0] + bsum[1] + bsum[2] + bsum[3]) * (1.0f / 8192.0f));
}

extern "C" void kernel_launch(void* const* d_in, const int* in_sizes, int n_in,
                              void* d_out, int out_size, void* d_ws, size_t ws_size,
                              hipStream_t stream) {
    const float* f10 = (const float*)d_in[0];
    const float* f11 = (const float*)d_in[1];
    const float* f20 = (const float*)d_in[2];
    const float* f21 = (const float*)d_in[3];
    float* Cmats = (float*)d_ws;          // 2*64*64*64 floats = 2 MB
    float* out = (float*)d_out;

    hipMemsetAsync(out, 0, sizeof(float), stream);  // harness poisons d_out
    build_cost<<<dim3(64, 2), 256, 0, stream>>>(f10, f11, f20, f21, Cmats);
    sinkhorn<<<dim3(16, 64, 2), 256, 0, stream>>>(f10, f11, f20, f21, Cmats, out);
}

// Round 2
// 106.004 us; speedup vs baseline: 2.2170x; 2.2170x over previous
//
#include <hip/hip_runtime.h>
#include <math.h>

// B = C = HW = 64; two pairs. loss = mean_{b,c} Sinkhorn(C[c], softmax rows).
// Sinkhorn in SCALING form (exact algebraic transform of the reference's
// log-domain Gauss-Seidel): a = (p1+1e-12)/(K b), b = (p2+1e-12)/(K^T a),
// K = exp(-C/eps), pi = a_s K_st b_t. eps=0.5 -> K in [0.135,1]: fp32-safe.

#define SINK_ITERS 5
#define LOGEPS 1e-12f
#define COSEPS 1e-8f

__device__ __forceinline__ float wave_sum(float v) {
    #pragma unroll
    for (int o = 32; o; o >>= 1) v += __shfl_xor(v, o);
    return v;
}
__device__ __forceinline__ float wave_max(float v) {
    #pragma unroll
    for (int o = 32; o; o >>= 1) v = fmaxf(v, __shfl_xor(v, o));
    return v;
}

// ---------------------------------------------------------------------------
// Kernel 1: cost + kernel matrices. grid = (c=64, p=2, tile=4), block = 256.
// Each block: rows i0..i0+15 of C[p][c]: rownorm(1 - cos(x1_i, x2_j)), and
// K = exp(-2C). Block (0,0,0) also zeroes d_out.
// ---------------------------------------------------------------------------
__global__ __launch_bounds__(256) void build_cost(
        const float* __restrict__ f10, const float* __restrict__ f11,
        const float* __restrict__ f20, const float* __restrict__ f21,
        float* __restrict__ Cout, float* __restrict__ Kout,
        float* __restrict__ out)
{
    const int c = blockIdx.x, p = blockIdx.y, tile = blockIdx.z;
    const float* x1 = p ? f11 : f10;
    const float* x2 = p ? f21 : f20;

    __shared__ float X2[64][65];    // stride 65: bank (j+k)%32, 2-way = free
    __shared__ float X1t[16][65];
    __shared__ float inv1[16], inv2[64];

    const int tid = threadIdx.x;
    const int base = c << 12;
    const int i0 = tile << 4;

    if (c == 0 && p == 0 && tile == 0 && tid == 0) out[0] = 0.f;

    for (int e = tid; e < 4096; e += 256) X2[e >> 6][e & 63] = x2[base + e];
    for (int e = tid; e < 1024; e += 256) X1t[e >> 6][e & 63] = x1[base + (i0 << 6) + e];
    __syncthreads();

    if (tid < 80) {
        const float* row = (tid < 64) ? X2[tid] : X1t[tid - 64];
        float s = 0.f;
        #pragma unroll 8
        for (int k = 0; k < 64; k++) { float v = row[k]; s += v * v; }
        float inv = 1.0f / fmaxf(sqrtf(s), COSEPS);
        if (tid < 64) inv2[tid] = inv; else inv1[tid - 64] = inv;
    }
    __syncthreads();

    const int mbase = (((p << 6) | c) << 12) + (i0 << 6);
    #pragma unroll
    for (int it = 0; it < 4; it++) {
        int e = tid + (it << 8);
        int i = e >> 6, j = e & 63;       // i wave-uniform, j = lane
        float acc = 0.f;
        #pragma unroll 8
        for (int k = 0; k < 64; k++) acc += X1t[i][k] * X2[j][k];
        float cv = 1.0f - acc * inv1[i] * inv2[j];
        // per-row min/max over j (the full row lives in this wave)
        float mn = cv, mx = cv;
        #pragma unroll
        for (int o = 32; o; o >>= 1) {
            mn = fminf(mn, __shfl_xor(mn, o));
            mx = fmaxf(mx, __shfl_xor(mx, o));
        }
        cv = (cv - mn) / (mx - mn);
        Cout[mbase + (i << 6) + j] = cv;
        Kout[mbase + (i << 6) + j] = __expf(-2.0f * cv);
    }
}

// ---------------------------------------------------------------------------
// Kernel 2: Sinkhorn scaling iterations. grid = (bg=4, c=64, p=2), block 256.
// 4 waves/block; each wave owns 4 b's (float4 register-blocked): one LDS read
// of K[s][t] feeds 4 fmas. Loop body is matvec + divide only.
// ---------------------------------------------------------------------------
__global__ __launch_bounds__(256) void sinkhorn(
        const float* __restrict__ f10, const float* __restrict__ f11,
        const float* __restrict__ f20, const float* __restrict__ f21,
        const float* __restrict__ Cmats, const float* __restrict__ Kmats,
        float* __restrict__ out)
{
    __shared__ float Ksh[64][65];
    __shared__ float Csh[64][65];
    __shared__ float4 ash[4][64];
    __shared__ float4 bsh[4][64];
    __shared__ float wsum[4];

    const int tid = threadIdx.x, w = tid >> 6, lane = tid & 63;
    const int bg = blockIdx.x, c = blockIdx.y, p = blockIdx.z;
    const float* x1 = p ? f11 : f10;
    const float* x2 = p ? f21 : f20;

    const int mbase = ((p << 6) | c) << 12;
    for (int e = tid; e < 4096; e += 256) {
        Ksh[e >> 6][e & 63] = Kmats[mbase + e];
        Csh[e >> 6][e & 63] = Cmats[mbase + e];
    }

    // marginals: p1[k], p2[k] for the 4 b's this wave owns (lane = hw index)
    const int b0 = (bg << 4) | (w << 2);
    float p1[4], p2[4];
    #pragma unroll
    for (int k = 0; k < 4; k++) {
        const int rowoff = (((b0 + k) << 6) | c) << 6;
        float xv1 = x1[rowoff + lane];
        float e1 = __expf(xv1 - wave_max(xv1));
        p1[k] = e1 / wave_sum(e1) + LOGEPS;
        float xv2 = x2[rowoff + lane];
        float e2 = __expf(xv2 - wave_max(xv2));
        p2[k] = e2 / wave_sum(e2) + LOGEPS;
    }

    bsh[w][lane] = make_float4(1.f, 1.f, 1.f, 1.f);
    float4 a;
    __syncthreads();

    for (int it = 0; it < SINK_ITERS; it++) {
        // u-step: lane = s, r = (K b)_s
        float4 r = make_float4(0.f, 0.f, 0.f, 0.f);
        #pragma unroll 8
        for (int t = 0; t < 64; t++) {
            float kv = Ksh[lane][t];
            float4 bv = bsh[w][t];
            r.x = fmaf(kv, bv.x, r.x);
            r.y = fmaf(kv, bv.y, r.y);
            r.z = fmaf(kv, bv.z, r.z);
            r.w = fmaf(kv, bv.w, r.w);
        }
        a.x = p1[0] / r.x; a.y = p1[1] / r.y;
        a.z = p1[2] / r.z; a.w = p1[3] / r.w;
        ash[w][lane] = a;
        __syncthreads();

        // v-step: lane = t, r = (K^T a)_t
        float4 r2 = make_float4(0.f, 0.f, 0.f, 0.f);
        #pragma unroll 8
        for (int s = 0; s < 64; s++) {
            float kv = Ksh[s][lane];
            float4 av = ash[w][s];
            r2.x = fmaf(kv, av.x, r2.x);
            r2.y = fmaf(kv, av.y, r2.y);
            r2.z = fmaf(kv, av.z, r2.z);
            r2.w = fmaf(kv, av.w, r2.w);
        }
        float4 bn;
        bn.x = p2[0] / r2.x; bn.y = p2[1] / r2.y;
        bn.z = p2[2] / r2.z; bn.w = p2[3] / r2.w;
        bsh[w][lane] = bn;
        __syncthreads();
    }

    // loss: sum_{s,t} a_s K_st b_t C_st   (lane = s, final a in regs)
    float4 acc = make_float4(0.f, 0.f, 0.f, 0.f);
    #pragma unroll 8
    for (int t = 0; t < 64; t++) {
        float kc = Ksh[lane][t] * Csh[lane][t];
        float4 bv = bsh[w][t];
        acc.x = fmaf(kc, bv.x, acc.x);
        acc.y = fmaf(kc, bv.y, acc.y);
        acc.z = fmaf(kc, bv.z, acc.z);
        acc.w = fmaf(kc, bv.w, acc.w);
    }
    float tot = wave_sum(acc.x * a.x + acc.y * a.y + acc.z * a.z + acc.w * a.w);
    if (lane == 0) wsum[w] = tot;
    __syncthreads();
    if (tid == 0)
        atomicAdd(out, (wsum[0] + wsum[1] + wsum[2] + wsum[3]) * (1.0f / 8192.0f));
}

extern "C" void kernel_launch(void* const* d_in, const int* in_sizes, int n_in,
                              void* d_out, int out_size, void* d_ws, size_t ws_size,
                              hipStream_t stream) {
    const float* f10 = (const float*)d_in[0];
    const float* f11 = (const float*)d_in[1];
    const float* f20 = (const float*)d_in[2];
    const float* f21 = (const float*)d_in[3];
    float* Cmats = (float*)d_ws;                     // 2 MB
    float* Kmats = (float*)d_ws + 2 * 64 * 64 * 64;  // 2 MB
    float* out = (float*)d_out;

    build_cost<<<dim3(64, 2, 4), 256, 0, stream>>>(f10, f11, f20, f21, Cmats, Kmats, out);
    sinkhorn<<<dim3(4, 64, 2), 256, 0, stream>>>(f10, f11, f20, f21, Cmats, Kmats, out);
}

// Round 3
// 103.813 us; speedup vs baseline: 2.2638x; 1.0211x over previous
//
#include <hip/hip_runtime.h>
#include <math.h>

// B = C = HW = 64; two pairs. loss = mean_{b,c} Sinkhorn(C[c], softmax rows).
// Scaling form (exact transform of the reference log-domain Gauss-Seidel):
//   a = (p1+1e-12)/(K b), b = (p2+1e-12)/(K^T a), K = exp(-C/eps).
// eps=0.5 -> K in [0.135,1]: fp32-safe. R2 validated absmax 0.0.
//
// R3: sinkhorn inner loop moved off the LDS pipe (was LDS-issue-bound:
// 128 b32 + 128 b128 per wave-iter ~ 2.3k LDS cyc x 8 waves/CU x 5 iters
// ~ 40 us). Now: K row+col live in 128 VGPRs per lane (loaded once from
// Ksh/KTsh), a/b broadcast via v_readlane (VALU, SGPR operand into fma).
// No __syncthreads in the iteration loop.

#define SINK_ITERS 5
#define LOGEPS 1e-12f
#define COSEPS 1e-8f

__device__ __forceinline__ float wave_sum(float v) {
    #pragma unroll
    for (int o = 32; o; o >>= 1) v += __shfl_xor(v, o);
    return v;
}
__device__ __forceinline__ float wave_max(float v) {
    #pragma unroll
    for (int o = 32; o; o >>= 1) v = fmaxf(v, __shfl_xor(v, o));
    return v;
}
__device__ __forceinline__ float bcast(float v, int l) {
    return __int_as_float(__builtin_amdgcn_readlane(__float_as_int(v), l));
}

// ---------------------------------------------------------------------------
// Kernel 1: cost + kernel matrices. grid = (c=64, p=2, tile=4), block = 256.
// (unchanged from R2 — proven correct; ~8 us, optimize later if it matters)
// ---------------------------------------------------------------------------
__global__ __launch_bounds__(256) void build_cost(
        const float* __restrict__ f10, const float* __restrict__ f11,
        const float* __restrict__ f20, const float* __restrict__ f21,
        float* __restrict__ Cout, float* __restrict__ Kout,
        float* __restrict__ out)
{
    const int c = blockIdx.x, p = blockIdx.y, tile = blockIdx.z;
    const float* x1 = p ? f11 : f10;
    const float* x2 = p ? f21 : f20;

    __shared__ float X2[64][65];    // stride 65: bank (j+k)%32, 2-way = free
    __shared__ float X1t[16][65];
    __shared__ float inv1[16], inv2[64];

    const int tid = threadIdx.x;
    const int base = c << 12;
    const int i0 = tile << 4;

    if (c == 0 && p == 0 && tile == 0 && tid == 0) out[0] = 0.f;

    for (int e = tid; e < 4096; e += 256) X2[e >> 6][e & 63] = x2[base + e];
    for (int e = tid; e < 1024; e += 256) X1t[e >> 6][e & 63] = x1[base + (i0 << 6) + e];
    __syncthreads();

    if (tid < 80) {
        const float* row = (tid < 64) ? X2[tid] : X1t[tid - 64];
        float s = 0.f;
        #pragma unroll 8
        for (int k = 0; k < 64; k++) { float v = row[k]; s += v * v; }
        float inv = 1.0f / fmaxf(sqrtf(s), COSEPS);
        if (tid < 64) inv2[tid] = inv; else inv1[tid - 64] = inv;
    }
    __syncthreads();

    const int mbase = (((p << 6) | c) << 12) + (i0 << 6);
    #pragma unroll
    for (int it = 0; it < 4; it++) {
        int e = tid + (it << 8);
        int i = e >> 6, j = e & 63;       // i wave-uniform, j = lane
        float acc = 0.f;
        #pragma unroll 8
        for (int k = 0; k < 64; k++) acc += X1t[i][k] * X2[j][k];
        float cv = 1.0f - acc * inv1[i] * inv2[j];
        float mn = cv, mx = cv;
        #pragma unroll
        for (int o = 32; o; o >>= 1) {
            mn = fminf(mn, __shfl_xor(mn, o));
            mx = fmaxf(mx, __shfl_xor(mx, o));
        }
        cv = (cv - mn) / (mx - mn);
        Cout[mbase + (i << 6) + j] = cv;
        Kout[mbase + (i << 6) + j] = __expf(-2.0f * cv);
    }
}

// ---------------------------------------------------------------------------
// Kernel 2: Sinkhorn scaling iterations, register-resident K.
// grid = (bg=4, c=64, p=2) = 512 blocks, 256 threads (4 waves), 4 b's/wave.
// lane s holds: K row s (kr[64]), K col s (kc[64]), a_s, b_s (x4 batches).
// Broadcasts via v_readlane -> pure-VALU inner loop, no barriers in it.
// ---------------------------------------------------------------------------
__global__ __launch_bounds__(256, 2) void sinkhorn(
        const float* __restrict__ f10, const float* __restrict__ f11,
        const float* __restrict__ f20, const float* __restrict__ f21,
        const float* __restrict__ Cmats, const float* __restrict__ Kmats,
        float* __restrict__ out)
{
    __shared__ float Ksh[64][65];
    __shared__ float KTsh[64][65];
    __shared__ float Csh[64][65];
    __shared__ float wsum[4];

    const int tid = threadIdx.x, w = tid >> 6, lane = tid & 63;
    const int bg = blockIdx.x, c = blockIdx.y, p = blockIdx.z;
    const float* x1 = p ? f11 : f10;
    const float* x2 = p ? f21 : f20;

    // stage K (both orientations) + C. lane = e&63, row uniform per wave:
    // Ksh banks (r+k)%32, KTsh banks (k+r)%32 -> both conflict-free.
    const int mbase = ((p << 6) | c) << 12;
    #pragma unroll
    for (int m = 0; m < 16; m++) {
        int e = tid + (m << 8);
        int r = e >> 6, k = e & 63;
        float kv = Kmats[mbase + e];
        Ksh[r][k] = kv;
        KTsh[k][r] = kv;
        Csh[r][k] = Cmats[mbase + e];
    }

    // marginals for this wave's 4 batches (lane = hw index)
    const int b0 = ((bg << 4) | (w << 2));
    float p1[4], p2[4];
    #pragma unroll
    for (int q = 0; q < 4; q++) {
        const int rowoff = (((b0 + q) << 6) | c) << 6;
        float xv1 = x1[rowoff + lane];
        float e1 = __expf(xv1 - wave_max(xv1));
        p1[q] = e1 / wave_sum(e1) + LOGEPS;
        float xv2 = x2[rowoff + lane];
        float e2 = __expf(xv2 - wave_max(xv2));
        p2[q] = e2 / wave_sum(e2) + LOGEPS;
    }
    __syncthreads();

    // K row + K column of this lane into registers (one-time LDS reads)
    float kr[64], kc[64];
    #pragma unroll
    for (int k = 0; k < 64; k++) kr[k] = Ksh[lane][k];
    #pragma unroll
    for (int k = 0; k < 64; k++) kc[k] = KTsh[lane][k];

    float a[4], b[4];
    #pragma unroll
    for (int q = 0; q < 4; q++) b[q] = 1.f;

    #pragma unroll 1
    for (int it = 0; it < SINK_ITERS; it++) {
        // u-step: lane = s, r = (K b)_s. b_t via readlane (SGPR broadcast).
        float r[4] = {0.f, 0.f, 0.f, 0.f};
        #pragma unroll
        for (int t = 0; t < 64; t++) {
            float kv = kr[t];
            #pragma unroll
            for (int q = 0; q < 4; q++)
                r[q] = fmaf(kv, bcast(b[q], t), r[q]);
        }
        #pragma unroll
        for (int q = 0; q < 4; q++) a[q] = p1[q] / r[q];

        // v-step: lane = t, r2 = (K^T a)_t. a_s via readlane.
        float r2[4] = {0.f, 0.f, 0.f, 0.f};
        #pragma unroll
        for (int s = 0; s < 64; s++) {
            float kv = kc[s];
            #pragma unroll
            for (int q = 0; q < 4; q++)
                r2[q] = fmaf(kv, bcast(a[q], s), r2[q]);
        }
        #pragma unroll
        for (int q = 0; q < 4; q++) b[q] = p2[q] / r2[q];
    }

    // loss: sum_{s,t} a_s K_st b_t C_st  (lane = s; C row from LDS, b via
    // readlane; LDS reads overlap the VALU stream here, one-time cost)
    float acc[4] = {0.f, 0.f, 0.f, 0.f};
    #pragma unroll
    for (int t = 0; t < 64; t++) {
        float kcst = kr[t] * Csh[lane][t];
        #pragma unroll
        for (int q = 0; q < 4; q++)
            acc[q] = fmaf(kcst, bcast(b[q], t), acc[q]);
    }
    float tot = wave_sum(acc[0] * a[0] + acc[1] * a[1] +
                         acc[2] * a[2] + acc[3] * a[3]);
    if (lane == 0) wsum[w] = tot;
    __syncthreads();
    if (tid == 0)
        atomicAdd(out, (wsum[0] + wsum[1] + wsum[2] + wsum[3]) * (1.0f / 8192.0f));
}

extern "C" void kernel_launch(void* const* d_in, const int* in_sizes, int n_in,
                              void* d_out, int out_size, void* d_ws, size_t ws_size,
                              hipStream_t stream) {
    const float* f10 = (const float*)d_in[0];
    const float* f11 = (const float*)d_in[1];
    const float* f20 = (const float*)d_in[2];
    const float* f21 = (const float*)d_in[3];
    float* Cmats = (float*)d_ws;                     // 2 MB
    float* Kmats = (float*)d_ws + 2 * 64 * 64 * 64;  // 2 MB
    float* out = (float*)d_out;

    build_cost<<<dim3(64, 2, 4), 256, 0, stream>>>(f10, f11, f20, f21, Cmats, Kmats, out);
    sinkhorn<<<dim3(4, 64, 2), 256, 0, stream>>>(f10, f11, f20, f21, Cmats, Kmats, out);
}

// Round 4
// 99.611 us; speedup vs baseline: 2.3593x; 1.0422x over previous
//
#include <hip/hip_runtime.h>
#include <math.h>

// B = C = HW = 64; two pairs. loss = mean_{b,c} Sinkhorn(C[c], softmax rows).
// Scaling form (exact transform of the reference log-domain Gauss-Seidel):
//   a = (p1+1e-12)/(K b), b = (p2+1e-12)/(K^T a), K = exp(-C/eps).
// eps=0.5 -> K in [0.135,1]: fp32-safe. Validated absmax 0.0 (R2/R3).
//
// R4: single fused kernel. Each block (bg,c,p) computes cost matrix C[c] and
// K=exp(-2C) directly in LDS (same total GEMM work as the old build_cost —
// 512 blocks either way), then runs the register-resident scaling iteration
// (K row+col in 128 VGPRs, a/b broadcast via v_readlane — pure VALU loop).
// Deletes: build_cost launch, 4 MB C/K global round-trip, duplicate staging.
// LDS stride 68: 17*lane mod 32 is a permutation -> conflict-free columns,
// and rows are 16B-aligned for ds_read_b128.

#define SINK_ITERS 5
#define LOGEPS 1e-12f
#define COSEPS 1e-8f

__device__ __forceinline__ float wave_sum(float v) {
    #pragma unroll
    for (int o = 32; o; o >>= 1) v += __shfl_xor(v, o);
    return v;
}
__device__ __forceinline__ float wave_max(float v) {
    #pragma unroll
    for (int o = 32; o; o >>= 1) v = fmaxf(v, __shfl_xor(v, o));
    return v;
}
__device__ __forceinline__ float bcast(float v, int l) {
    return __int_as_float(__builtin_amdgcn_readlane(__float_as_int(v), l));
}

// grid = (bg=4, c=64, p=2) = 512 blocks, 256 threads (4 waves), 4 b's/wave.
__global__ __launch_bounds__(256, 2) void emd_fused(
        const float* __restrict__ f10, const float* __restrict__ f11,
        const float* __restrict__ f20, const float* __restrict__ f21,
        float* __restrict__ out)
{
    __shared__ float Ksh[64][68];    // phase 1: X1 staging; phase 2: K
    __shared__ float KTsh[64][68];   // K transposed
    __shared__ float Csh[64][68];    // normalized cost
    __shared__ float inv1[64];
    __shared__ float wsum[4];

    const int tid = threadIdx.x, w = tid >> 6, lane = tid & 63;
    const int bg = blockIdx.x, c = blockIdx.y, p = blockIdx.z;
    const float* x1 = p ? f11 : f10;
    const float* x2 = p ? f21 : f20;

    // ---- marginals for this wave's 4 batches (global + shuffles only)
    const int b0 = (bg << 4) | (w << 2);
    float p1[4], p2[4];
    #pragma unroll
    for (int q = 0; q < 4; q++) {
        const int rowoff = (((b0 + q) << 6) | c) << 6;
        float xv1 = x1[rowoff + lane];
        float e1 = __expf(xv1 - wave_max(xv1));
        p1[q] = e1 / wave_sum(e1) + LOGEPS;
        float xv2 = x2[rowoff + lane];
        float e2 = __expf(xv2 - wave_max(xv2));
        p2[q] = e2 / wave_sum(e2) + LOGEPS;
    }

    // ---- stage X1 (batch c) rows into Ksh, float4 loads
    const int base = c << 12;
    const float4* x1g = (const float4*)(x1 + base);
    #pragma unroll
    for (int m = 0; m < 4; m++) {
        int idx = tid + (m << 8);            // 1024 float4 = 4096 floats
        float4 v = x1g[idx];
        int r = idx >> 4, k0 = (idx & 15) << 2;
        Ksh[r][k0] = v.x; Ksh[r][k0 + 1] = v.y;
        Ksh[r][k0 + 2] = v.z; Ksh[r][k0 + 3] = v.w;
    }

    // ---- x2 row j=lane into registers + its inverse norm (register only)
    float x2r[64];
    const float4* x2g = (const float4*)(x2 + base + (lane << 6));
    float ss2 = 0.f;
    #pragma unroll
    for (int k4 = 0; k4 < 16; k4++) {
        float4 v = x2g[k4];
        x2r[4 * k4] = v.x; x2r[4 * k4 + 1] = v.y;
        x2r[4 * k4 + 2] = v.z; x2r[4 * k4 + 3] = v.w;
        ss2 += v.x * v.x + v.y * v.y + v.z * v.z + v.w * v.w;
    }
    const float i2 = 1.0f / fmaxf(sqrtf(ss2), COSEPS);
    __syncthreads();

    // ---- X1 row norms
    if (tid < 64) {
        float s = 0.f;
        #pragma unroll 8
        for (int k = 0; k < 64; k++) { float v = Ksh[tid][k]; s += v * v; }
        inv1[tid] = 1.0f / fmaxf(sqrtf(s), COSEPS);
    }
    __syncthreads();

    // ---- cosine GEMM + per-row min/max norm. Each thread: 16 rows i, col
    // j=lane. X1 row read as uniform-address b128 broadcasts; X2 row in regs.
    float kvr[16];
    #pragma unroll
    for (int m = 0; m < 16; m++) {
        const int i = (m << 2) | w;
        const float4* xr = (const float4*)(&Ksh[i][0]);
        float acc = 0.f;
        #pragma unroll
        for (int k4 = 0; k4 < 16; k4++) {
            float4 xv = xr[k4];
            acc = fmaf(xv.x, x2r[4 * k4], acc);
            acc = fmaf(xv.y, x2r[4 * k4 + 1], acc);
            acc = fmaf(xv.z, x2r[4 * k4 + 2], acc);
            acc = fmaf(xv.w, x2r[4 * k4 + 3], acc);
        }
        float cv = 1.0f - acc * inv1[i] * i2;
        float mn = cv, mx = cv;                 // row i complete in this wave
        #pragma unroll
        for (int o = 32; o; o >>= 1) {
            mn = fminf(mn, __shfl_xor(mn, o));
            mx = fmaxf(mx, __shfl_xor(mx, o));
        }
        cv = (cv - mn) / (mx - mn);
        Csh[i][lane] = cv;
        float kv = __expf(-2.0f * cv);
        KTsh[lane][i] = kv;                     // KTsh fresh: no hazard
        kvr[m] = kv;                            // Ksh still holds X1: defer
    }
    __syncthreads();
    #pragma unroll
    for (int m = 0; m < 16; m++) Ksh[(m << 2) | w][lane] = kvr[m];
    __syncthreads();

    // ---- K row + column of this lane into registers (b128, 16B-aligned)
    float kr[64], kc[64];
    {
        const float4* rrow = (const float4*)(&Ksh[lane][0]);
        const float4* rcol = (const float4*)(&KTsh[lane][0]);
        #pragma unroll
        for (int k4 = 0; k4 < 16; k4++) {
            float4 a4 = rrow[k4];
            kr[4 * k4] = a4.x; kr[4 * k4 + 1] = a4.y;
            kr[4 * k4 + 2] = a4.z; kr[4 * k4 + 3] = a4.w;
            float4 b4 = rcol[k4];
            kc[4 * k4] = b4.x; kc[4 * k4 + 1] = b4.y;
            kc[4 * k4 + 2] = b4.z; kc[4 * k4 + 3] = b4.w;
        }
    }

    // ---- scaling iterations: pure VALU (readlane broadcasts), no barriers
    float a[4], b[4];
    #pragma unroll
    for (int q = 0; q < 4; q++) b[q] = 1.f;

    #pragma unroll 1
    for (int it = 0; it < SINK_ITERS; it++) {
        float r[4] = {0.f, 0.f, 0.f, 0.f};      // u-step: lane = s
        #pragma unroll
        for (int t = 0; t < 64; t++) {
            float kv = kr[t];
            #pragma unroll
            for (int q = 0; q < 4; q++)
                r[q] = fmaf(kv, bcast(b[q], t), r[q]);
        }
        #pragma unroll
        for (int q = 0; q < 4; q++) a[q] = p1[q] / r[q];

        float r2[4] = {0.f, 0.f, 0.f, 0.f};     // v-step: lane = t
        #pragma unroll
        for (int s = 0; s < 64; s++) {
            float kv = kc[s];
            #pragma unroll
            for (int q = 0; q < 4; q++)
                r2[q] = fmaf(kv, bcast(a[q], s), r2[q]);
        }
        #pragma unroll
        for (int q = 0; q < 4; q++) b[q] = p2[q] / r2[q];
    }

    // ---- loss: sum_{s,t} a_s K_st b_t C_st  (lane = s; C row b128 reads)
    float acc[4] = {0.f, 0.f, 0.f, 0.f};
    const float4* crow = (const float4*)(&Csh[lane][0]);
    #pragma unroll
    for (int t4 = 0; t4 < 16; t4++) {
        float4 cv = crow[t4];
        float kc0 = kr[4 * t4] * cv.x;
        float kc1 = kr[4 * t4 + 1] * cv.y;
        float kc2 = kr[4 * t4 + 2] * cv.z;
        float kc3 = kr[4 * t4 + 3] * cv.w;
        #pragma unroll
        for (int q = 0; q < 4; q++) {
            acc[q] = fmaf(kc0, bcast(b[q], 4 * t4), acc[q]);
            acc[q] = fmaf(kc1, bcast(b[q], 4 * t4 + 1), acc[q]);
            acc[q] = fmaf(kc2, bcast(b[q], 4 * t4 + 2), acc[q]);
            acc[q] = fmaf(kc3, bcast(b[q], 4 * t4 + 3), acc[q]);
        }
    }
    float tot = wave_sum(acc[0] * a[0] + acc[1] * a[1] +
                         acc[2] * a[2] + acc[3] * a[3]);
    if (lane == 0) wsum[w] = tot;
    __syncthreads();
    if (tid == 0)
        atomicAdd(out, (wsum[0] + wsum[1] + wsum[2] + wsum[3]) * (1.0f / 8192.0f));
}

extern "C" void kernel_launch(void* const* d_in, const int* in_sizes, int n_in,
                              void* d_out, int out_size, void* d_ws, size_t ws_size,
                              hipStream_t stream) {
    const float* f10 = (const float*)d_in[0];
    const float* f11 = (const float*)d_in[1];
    const float* f20 = (const float*)d_in[2];
    const float* f21 = (const float*)d_in[3];
    float* out = (float*)d_out;

    hipMemsetAsync(out, 0, sizeof(float), stream);
    emd_fused<<<dim3(4, 64, 2), 256, 0, stream>>>(f10, f11, f20, f21, out);
}